// Round 3
// baseline (309.961 us; speedup 1.0000x reference)
//
#include <hip/hip_runtime.h>
#include <hip/hip_bf16.h>
#include <cstdint>
#include <cstddef>

// ---------------------------------------------------------------------------
// CausalSelfAttention: x[2,4096,768] fp32, W_qkv[768,2304], b_qkv, W_proj[768,768], b_proj
// bf16 MFMA. All staging via __builtin_amdgcn_global_load_lds(16B) with
// XOR-swizzled source chunks (LDS dest is wave-contiguous => no padding; the
// swizzle c^=row&7 makes fragment reads bank-conflict-free instead).
// Attention: persistent 4-wave blocks + atomic queue; P stays in registers
// via mfma_16x16x16bf16_1k (S^T C-layout == PV B-operand layout).
// R4 lesson: never hold staging loads in VGPRs across compute (spills).
// R6 lesson: LDS staging is mandatory for 4-wave-reused operands.
// R7 lesson: dbuf + counted vmcnt prefetch = NEUTRAL (cross-block TLP already
// hides staging latency at 3 blocks/CU).
// R8 lesson: removing the mid-tile barrier = REGRESSION (-11%); the R6
// lockstep schedule is the right one. Scheduling-overlap is a dead end here.
// R9 (this round): the cost that remains is per-tile FIXED overhead
// (2 drains/barriers, addr setup, loop control) x 25,344 tiles. Amortize:
// 128-key staged tiles (Ks[128][64] + Vs[64][128] = 32KB, same occupancy),
// computed as two 64-key sub-passes with UNCHANGED register footprint.
// Tile count halves to 12,672. Predicted attn 124 -> ~100-108us.
// ---------------------------------------------------------------------------

typedef __attribute__((ext_vector_type(8))) short bf16x8;   // 8 bf16 = 4 VGPRs
typedef __attribute__((ext_vector_type(4))) short bf16x4;   // 4 bf16 = 2 VGPRs
typedef __attribute__((ext_vector_type(4))) float f32x4;

#define MFMA16(a, b, c)   __builtin_amdgcn_mfma_f32_16x16x32_bf16((a), (b), (c), 0, 0, 0)
#define MFMA16K(a, b, c)  __builtin_amdgcn_mfma_f32_16x16x16bf16_1k((a), (b), (c), 0, 0, 0)

static constexpr int Bc = 2, Tc = 4096, Dc = 768, Hc = 12, DKc = 64;
static constexpr int BHc = Bc * Hc;      // 24
static constexpr int Mc = Bc * Tc;       // 8192
static constexpr int Nqkv = 3 * Dc;      // 2304
static constexpr int NQBLK = Tc / 128;   // 32 Q-blocks per bh
static constexpr unsigned int NITEMS = BHc * NQBLK;  // 768 work items

__device__ __forceinline__ unsigned short f2bf(float f) {
    union { float f; unsigned int i; } c; c.f = f;
    unsigned int x = c.i;
    return (unsigned short)((x + 0x7fffu + ((x >> 16) & 1u)) >> 16); // RNE
}
__device__ __forceinline__ unsigned int pkbf(float a, float b) {
    __hip_bfloat162 h = __float22bfloat162_rn(make_float2(a, b));   // v_cvt_pk_bf16_f32
    union { __hip_bfloat162 h; unsigned int u; } c; c.h = h;
    return c.u;
}
// async global->LDS, 16B per lane; LDS dest = wave-uniform base + lane*16
__device__ __forceinline__ void glds16(const unsigned short* g, unsigned short* l) {
    __builtin_amdgcn_global_load_lds(
        (const __attribute__((address_space(1))) unsigned int*)g,
        (__attribute__((address_space(3))) unsigned int*)l, 16, 0, 0);
}

// ---------------------------------------------------------------------------
// x fp32 -> bf16, flat copy.
// ---------------------------------------------------------------------------
__global__ __launch_bounds__(256)
void xconv_kernel(const float* __restrict__ X, unsigned short* __restrict__ Xb) {
    size_t i = ((size_t)blockIdx.x * 256 + threadIdx.x) * 8;
    float4 a = *(const float4*)(X + i);
    float4 b = *(const float4*)(X + i + 4);
    uint4 o;
    o.x = pkbf(a.x, a.y); o.y = pkbf(a.z, a.w);
    o.z = pkbf(b.x, b.y); o.w = pkbf(b.z, b.w);
    *(uint4*)(Xb + i) = o;
}

// ---------------------------------------------------------------------------
// W [K][N] fp32 -> WT [N][K] bf16.  grid (K/64, N/64), 256 thr.
// ---------------------------------------------------------------------------
__global__ __launch_bounds__(256)
void wtrans_kernel(const float* __restrict__ W, unsigned short* __restrict__ WT,
                   int K, int N) {
    __shared__ __align__(16) unsigned short tile[64 * 72];
    const int k0 = blockIdx.x * 64;
    const int n0 = blockIdx.y * 64;
    const int tid = threadIdx.x;
#pragma unroll
    for (int it = 0; it < 4; ++it) {
        int s = tid + it * 256;
        int r = s >> 4, g = s & 15;
        float4 v = *(const float4*)(W + (size_t)(k0 + r) * N + n0 + g * 4);
        ushort4 u;
        u.x = f2bf(v.x); u.y = f2bf(v.y); u.z = f2bf(v.z); u.w = f2bf(v.w);
        *(ushort4*)(tile + r * 72 + g * 4) = u;
    }
    __syncthreads();
#pragma unroll
    for (int it = 0; it < 2; ++it) {
        int s = tid + it * 256;
        int n = s >> 3, g = s & 7;
        unsigned int p0 = (unsigned int)tile[(g * 8 + 0) * 72 + n] |
                          ((unsigned int)tile[(g * 8 + 1) * 72 + n] << 16);
        unsigned int p1 = (unsigned int)tile[(g * 8 + 2) * 72 + n] |
                          ((unsigned int)tile[(g * 8 + 3) * 72 + n] << 16);
        unsigned int p2 = (unsigned int)tile[(g * 8 + 4) * 72 + n] |
                          ((unsigned int)tile[(g * 8 + 5) * 72 + n] << 16);
        unsigned int p3 = (unsigned int)tile[(g * 8 + 6) * 72 + n] |
                          ((unsigned int)tile[(g * 8 + 7) * 72 + n] << 16);
        uint4 o; o.x = p0; o.y = p1; o.z = p2; o.w = p3;
        *(uint4*)(WT + (size_t)(n0 + n) * K + k0 + g * 8) = o;
    }
}

// ---------------------------------------------------------------------------
// QKV GEMM: Xb[8192][768] bf16 x WqT[2304][768] bf16 (+bias) -> Q/K [bh][t][dk],
// V transposed to Vt [bh][dk][t]. Q pre-scaled by 0.125*log2(e).
// BK=64, global_load_lds staging, XOR-swizzled chunks. grid (64,18).
// ---------------------------------------------------------------------------
__global__ __launch_bounds__(256)
void qkv_gemm_kernel(const unsigned short* __restrict__ Xb,
                     const unsigned short* __restrict__ WT,
                     const float* __restrict__ bias,
                     unsigned short* __restrict__ Qb, unsigned short* __restrict__ Kb,
                     unsigned short* __restrict__ Vt) {
    __shared__ __align__(16) unsigned short As[128 * 64];  // [row][64K], swizzled
    __shared__ __align__(16) unsigned short Bs[128 * 64];
    const int tid = threadIdx.x;
    const int wave = tid >> 6, lane = tid & 63;
    const int quad = lane >> 4, l15 = lane & 15;
    const int wr = wave >> 1, wc = wave & 1;
    const int r0 = blockIdx.x * 128, c0 = blockIdx.y * 128;
    const int sw = l15 & 7;   // fragment-read swizzle key (row&7 == l15&7)

    f32x4 acc[4][4];
#pragma unroll
    for (int i = 0; i < 4; ++i)
#pragma unroll
        for (int j = 0; j < 4; ++j) acc[i][j] = (f32x4){0.f, 0.f, 0.f, 0.f};

    for (int k0 = 0; k0 < Dc; k0 += 64) {
#pragma unroll
        for (int it = 0; it < 4; ++it) {      // stage 128x64 A and B tiles
            int idx = it * 256 + tid;
            int r = idx >> 3, c = idx & 7;
            int cg = c ^ (r & 7);             // LDS slot c holds global chunk cg
            glds16(Xb + (size_t)(r0 + r) * Dc + k0 + cg * 8, As + idx * 8);
            glds16(WT + (size_t)(c0 + r) * Dc + k0 + cg * 8, Bs + idx * 8);
        }
        __syncthreads();
#pragma unroll
        for (int f = 0; f < 2; ++f) {
            bf16x8 af[4], bfr[4];
#pragma unroll
            for (int mt = 0; mt < 4; ++mt)
                af[mt] = *(const bf16x8*)(As + (wr * 64 + mt * 16 + l15) * 64 +
                                          (((f * 4 + quad) ^ sw) * 8));
#pragma unroll
            for (int nt = 0; nt < 4; ++nt)
                bfr[nt] = *(const bf16x8*)(Bs + (wc * 64 + nt * 16 + l15) * 64 +
                                           (((f * 4 + quad) ^ sw) * 8));
#pragma unroll
            for (int mt = 0; mt < 4; ++mt)
#pragma unroll
                for (int nt = 0; nt < 4; ++nt)
                    acc[mt][nt] = MFMA16(af[mt], bfr[nt], acc[mt][nt]);
        }
        __syncthreads();
    }

    const int part = c0 / Dc;
    const int cbase = c0 - part * Dc;
    const float scale = (part == 0) ? 0.125f * 1.4426950408889634f : 1.0f;
    float bv[4];
#pragma unroll
    for (int nt = 0; nt < 4; ++nt) bv[nt] = bias[c0 + wc * 64 + nt * 16 + l15];

    if (part < 2) {
        unsigned short* dstbuf = (part == 0) ? Qb : Kb;
#pragma unroll
        for (int mt = 0; mt < 4; ++mt)
#pragma unroll
            for (int reg = 0; reg < 4; ++reg) {
                int gr = r0 + wr * 64 + mt * 16 + quad * 4 + reg;
                int b = gr >> 12, t = gr & 4095;
#pragma unroll
                for (int nt = 0; nt < 4; ++nt) {
                    int cc = cbase + wc * 64 + nt * 16 + l15;
                    int h = cc >> 6, dk = cc & 63;
                    float v = (acc[mt][nt][reg] + bv[nt]) * scale;
                    dstbuf[((size_t)(b * Hc + h) * Tc + t) * DKc + dk] = f2bf(v);
                }
            }
    } else {
        // V: write transposed [bh][dk][t]
#pragma unroll
        for (int mt = 0; mt < 4; ++mt)
#pragma unroll
            for (int reg = 0; reg < 4; ++reg) {
                int gr = r0 + wr * 64 + mt * 16 + quad * 4 + reg;
                int b = gr >> 12, t = gr & 4095;
#pragma unroll
                for (int nt = 0; nt < 4; ++nt) {
                    int cc = cbase + wc * 64 + nt * 16 + l15;
                    int h = cc >> 6, dk = cc & 63;
                    float v = acc[mt][nt][reg] + bv[nt];
                    Vt[((size_t)(b * Hc + h) * DKc + dk) * Tc + t] = f2bf(v);
                }
            }
    }
}

// ---------------------------------------------------------------------------
// Flash attention: persistent 4-wave blocks + atomic queue, 768 items of
// (bh, 128 Q rows), longest first. R6-proven lockstep schedule, but with
// 128-key staged tiles computed as two 64-key sub-passes:
//   stage Ks[128][64] + Vs[64][128] (8 glds/wave, swizzled chunks);
//   __syncthreads (drain);
//   h=0: frag reads -> QK -> mask? -> exp/pack -> PV    (compiler lgkm waits)
//   h=1: frag reads -> lgkmcnt(0)+barrier (buffer free EARLY, waves finishing
//        may proceed to next stage) -> QK -> mask? -> exp/pack -> PV
// Tile count halves vs 64-key tiles => half the drains/barriers/addr setup.
//   S^T = MFMA16(kf,qf) C-layout (key=16mt+quad*4+reg, q=l15);
//   fixed-max softmax: exp2 (log2e folded into Q), per-lane partials;
//   P packed bf16x4 in-register == B operand of mfma_16x16x16bf16_1k;
//   O^T += V^T P^T, C-layout -> per-lane scalar 1/l, direct store.
//   MFMA clusters wrapped in s_setprio(1)/(0) (T5).
// ---------------------------------------------------------------------------
__global__ __launch_bounds__(256)
void attn_kernel(const unsigned short* __restrict__ Qb,
                 const unsigned short* __restrict__ Kb,
                 const unsigned short* __restrict__ Vt,
                 unsigned short* __restrict__ attn,
                 unsigned int* __restrict__ counter) {
    __shared__ __align__(16) unsigned short Ks[128 * 64];   // [key][dk], 8 16B-chunks/row
    __shared__ __align__(16) unsigned short Vs[64 * 128];   // [dk][key], 16 16B-chunks/row
    __shared__ unsigned int s_w;
    const int tid = threadIdx.x;
    const int wave = tid >> 6, lane = tid & 63;
    const int quad = lane >> 4, l15 = lane & 15;
    const int sw = l15 & 7;

    for (;;) {
        if (tid == 0) s_w = atomicAdd(counter, 1u);
        __syncthreads();
        const unsigned int w = s_w;
        if (w >= NITEMS) break;
        const int bh = (int)(w % (unsigned)BHc);
        const int i0 = (NQBLK - 1 - (int)(w / (unsigned)BHc)) * 128;  // longest first
        const unsigned short* Qp = Qb + (size_t)bh * Tc * DKc;
        const unsigned short* Kp = Kb + (size_t)bh * Tc * DKc;
        const unsigned short* Vp = Vt + (size_t)bh * DKc * Tc;

        // Q fragments for this wave's 32 rows (pre-scaled 0.125*log2e)
        bf16x8 qf[2][2];
#pragma unroll
        for (int qg = 0; qg < 2; ++qg)
#pragma unroll
            for (int f = 0; f < 2; ++f)
                qf[qg][f] = *(const bf16x8*)(Qp +
                    (size_t)(i0 + wave * 32 + qg * 16 + l15) * DKc + f * 32 + quad * 8);

        f32x4 lp[2] = {(f32x4){0.f,0.f,0.f,0.f}, (f32x4){0.f,0.f,0.f,0.f}};
        f32x4 o[2][4];
#pragma unroll
        for (int qg = 0; qg < 2; ++qg)
#pragma unroll
            for (int d = 0; d < 4; ++d) o[qg][d] = (f32x4){0.f, 0.f, 0.f, 0.f};

        const int nbig = (i0 >> 7) + 1;                    // 128-key tiles
        for (int jt = 0; jt < nbig; ++jt) {
            const int j0 = jt * 128;
            // stage K[128][64] and V^T[64][128], swizzled chunks, 8 glds/wave
#pragma unroll
            for (int it = 0; it < 4; ++it) {
                int idx = it * 256 + tid;
                int rk = idx >> 3, ck = idx & 7;           // K: 128 rows x 8 chunks
                glds16(Kp + (size_t)(j0 + rk) * DKc + ((ck ^ (rk & 7)) * 8), Ks + idx * 8);
                int rv = idx >> 4, cv = idx & 15;          // V: 64 rows x 16 chunks
                glds16(Vp + (size_t)rv * Tc + j0 + ((cv ^ (rv & 7)) * 8), Vs + idx * 8);
            }
            __syncthreads();

            const bool last = (jt == nbig - 1);
#pragma unroll
            for (int h = 0; h < 2; ++h) {                  // two 64-key sub-passes
                bf16x8 kf[2][4];
                bf16x4 vf[4][4];
#pragma unroll
                for (int f = 0; f < 2; ++f)
#pragma unroll
                    for (int mt = 0; mt < 4; ++mt)
                        kf[f][mt] = *(const bf16x8*)(Ks + (h * 64 + mt * 16 + l15) * 64 +
                                                     (((f * 4 + quad) ^ sw) * 8));
#pragma unroll
                for (int d = 0; d < 4; ++d)
#pragma unroll
                    for (int mt = 0; mt < 4; ++mt) {
                        int g8 = h * 8 + mt * 2 + (quad >> 1);   // 16B chunk of row
                        vf[d][mt] = *(const bf16x4*)(Vs + (d * 16 + l15) * 128 +
                                                     ((g8 ^ sw) * 8) + (quad & 1) * 4);
                    }
                if (h == 1) {
                    // all reads of the buffer done -> barrier EARLY so waves
                    // finishing compute can proceed to the next stage
                    asm volatile("s_waitcnt lgkmcnt(0)" ::: "memory");
                    __builtin_amdgcn_s_barrier();
                }

                // S^T: C-layout key=16mt+quad*4+reg, q=l15; both q-groups
                f32x4 sc[2][4];
#pragma unroll
                for (int qg = 0; qg < 2; ++qg)
#pragma unroll
                    for (int mt = 0; mt < 4; ++mt) sc[qg][mt] = (f32x4){0.f, 0.f, 0.f, 0.f};
                __builtin_amdgcn_s_setprio(1);
#pragma unroll
                for (int f = 0; f < 2; ++f)
#pragma unroll
                    for (int mt = 0; mt < 4; ++mt) {
                        sc[0][mt] = MFMA16(kf[f][mt], qf[0][f], sc[0][mt]);
                        sc[1][mt] = MFMA16(kf[f][mt], qf[1][f], sc[1][mt]);
                    }
                __builtin_amdgcn_s_setprio(0);

                if (last) {                                // diagonal region
#pragma unroll
                    for (int qg = 0; qg < 2; ++qg) {
                        int qrow = wave * 32 + qg * 16 + l15;
#pragma unroll
                        for (int mt = 0; mt < 4; ++mt)
#pragma unroll
                            for (int reg = 0; reg < 4; ++reg)
                                if (h * 64 + mt * 16 + quad * 4 + reg > qrow)
                                    sc[qg][mt][reg] = -1e30f;
                    }
                }

                // exp2 + partial row sums + pack P^T (B-operand, in-register)
                union { uint2 u; bf16x4 v; } pb[2][4];
#pragma unroll
                for (int qg = 0; qg < 2; ++qg)
#pragma unroll
                    for (int mt = 0; mt < 4; ++mt) {
#pragma unroll
                        for (int reg = 0; reg < 4; ++reg)
                            sc[qg][mt][reg] = __builtin_amdgcn_exp2f(sc[qg][mt][reg]);
                        lp[qg] += sc[qg][mt];
                        pb[qg][mt].u.x = pkbf(sc[qg][mt][0], sc[qg][mt][1]);
                        pb[qg][mt].u.y = pkbf(sc[qg][mt][2], sc[qg][mt][3]);
                    }

                // O^T += V^T P^T
                __builtin_amdgcn_s_setprio(1);
#pragma unroll
                for (int mt = 0; mt < 4; ++mt)
#pragma unroll
                    for (int d = 0; d < 4; ++d) {
                        o[0][d] = MFMA16K(vf[d][mt], pb[0][mt].v, o[0][d]);
                        o[1][d] = MFMA16K(vf[d][mt], pb[1][mt].v, o[1][d]);
                    }
                __builtin_amdgcn_s_setprio(0);
            }
        }

        // normalize + store: lane owns q = i0+wave*32+qg*16+l15 for all o
        const int b = bh / Hc, h = bh % Hc;
#pragma unroll
        for (int qg = 0; qg < 2; ++qg) {
            float ls = lp[qg][0] + lp[qg][1] + lp[qg][2] + lp[qg][3];
            ls += __shfl_xor(ls, 16);
            ls += __shfl_xor(ls, 32);
            float li = 1.0f / ls;
            int t = i0 + wave * 32 + qg * 16 + l15;
            unsigned short* dst = attn + (size_t)(b * Tc + t) * Dc + h * 64;
#pragma unroll
            for (int d = 0; d < 4; ++d) {
                uint2 u;
                u.x = pkbf(o[qg][d][0] * li, o[qg][d][1] * li);
                u.y = pkbf(o[qg][d][2] * li, o[qg][d][3] * li);
                *(uint2*)(dst + d * 16 + quad * 4) = u;
            }
        }
    }
}

// ---------------------------------------------------------------------------
// Proj GEMM: A[8192][768] bf16 x WpT[768][768] bf16 (+bias) -> out fp32
// BK=64, global_load_lds staging, XOR-swizzled. grid (64, 6), 256 thr.
// ---------------------------------------------------------------------------
__global__ __launch_bounds__(256)
void proj_gemm_kernel(const unsigned short* __restrict__ A,
                      const unsigned short* __restrict__ WT,
                      const float* __restrict__ bias, float* __restrict__ out) {
    __shared__ __align__(16) unsigned short As[128 * 64];
    __shared__ __align__(16) unsigned short Bs[128 * 64];
    const int tid = threadIdx.x;
    const int wave = tid >> 6, lane = tid & 63;
    const int quad = lane >> 4, l15 = lane & 15;
    const int wr = wave >> 1, wc = wave & 1;
    const int r0 = blockIdx.x * 128, c0 = blockIdx.y * 128;
    const int sw = l15 & 7;

    f32x4 acc[4][4];
#pragma unroll
    for (int i = 0; i < 4; ++i)
#pragma unroll
        for (int j = 0; j < 4; ++j) acc[i][j] = (f32x4){0.f, 0.f, 0.f, 0.f};

    for (int k0 = 0; k0 < Dc; k0 += 64) {
#pragma unroll
        for (int it = 0; it < 4; ++it) {
            int idx = it * 256 + tid;
            int r = idx >> 3, c = idx & 7;
            int cg = c ^ (r & 7);
            glds16(A + (size_t)(r0 + r) * Dc + k0 + cg * 8, As + idx * 8);
            glds16(WT + (size_t)(c0 + r) * Dc + k0 + cg * 8, Bs + idx * 8);
        }
        __syncthreads();
#pragma unroll
        for (int f = 0; f < 2; ++f) {
            bf16x8 af[4], bfr[4];
#pragma unroll
            for (int mt = 0; mt < 4; ++mt)
                af[mt] = *(const bf16x8*)(As + (wr * 64 + mt * 16 + l15) * 64 +
                                          (((f * 4 + quad) ^ sw) * 8));
#pragma unroll
            for (int nt = 0; nt < 4; ++nt)
                bfr[nt] = *(const bf16x8*)(Bs + (wc * 64 + nt * 16 + l15) * 64 +
                                           (((f * 4 + quad) ^ sw) * 8));
#pragma unroll
            for (int mt = 0; mt < 4; ++mt)
#pragma unroll
                for (int nt = 0; nt < 4; ++nt)
                    acc[mt][nt] = MFMA16(af[mt], bfr[nt], acc[mt][nt]);
        }
        __syncthreads();
    }

    float bv[4];
#pragma unroll
    for (int nt = 0; nt < 4; ++nt) bv[nt] = bias[c0 + wc * 64 + nt * 16 + l15];
#pragma unroll
    for (int mt = 0; mt < 4; ++mt)
#pragma unroll
        for (int reg = 0; reg < 4; ++reg) {
            int gr = r0 + wr * 64 + mt * 16 + quad * 4 + reg;
#pragma unroll
            for (int nt = 0; nt < 4; ++nt) {
                int gc = c0 + wc * 64 + nt * 16 + l15;
                out[(size_t)gr * Dc + gc] = acc[mt][nt][reg] + bv[nt];
            }
        }
}

// ---------------------------------------------------------------------------
extern "C" void kernel_launch(void* const* d_in, const int* in_sizes, int n_in,
                              void* d_out, int out_size, void* d_ws, size_t ws_size,
                              hipStream_t stream) {
    const float* x      = (const float*)d_in[0];
    const float* W_qkv  = (const float*)d_in[1];
    const float* b_qkv  = (const float*)d_in[2];
    const float* W_proj = (const float*)d_in[3];
    const float* b_proj = (const float*)d_in[4];
    float* out = (float*)d_out;

    char* ws = (char*)d_ws;
    size_t off = 0;
    auto take = [&](size_t bytes) -> char* {
        char* p = ws + off;
        off += (bytes + 255) & ~(size_t)255;
        return p;
    };
    unsigned int*   cnt = (unsigned int*)take(256);
    unsigned short* WqT = (unsigned short*)take((size_t)Nqkv * Dc * 2);  // [2304][768]
    unsigned short* WpT = (unsigned short*)take((size_t)Dc * Dc * 2);    // [768][768]
    unsigned short* Qb  = (unsigned short*)take((size_t)BHc * Tc * DKc * 2);
    unsigned short* Kb  = (unsigned short*)take((size_t)BHc * Tc * DKc * 2);
    unsigned short* Vt  = (unsigned short*)take((size_t)BHc * Tc * DKc * 2);
    unsigned short* Xb  = (unsigned short*)take((size_t)Mc * Dc * 2);
    unsigned short* An  = Xb;  // alias: Xb dead after qkv_gemm

    hipMemsetAsync(cnt, 0, sizeof(unsigned int), stream);
    xconv_kernel<<<dim3((Mc * Dc) / (256 * 8)), dim3(256), 0, stream>>>(x, Xb);
    wtrans_kernel<<<dim3(Dc / 64, Nqkv / 64), dim3(256), 0, stream>>>(W_qkv, WqT, Dc, Nqkv);
    wtrans_kernel<<<dim3(Dc / 64, Dc / 64), dim3(256), 0, stream>>>(W_proj, WpT, Dc, Dc);
    qkv_gemm_kernel<<<dim3(Mc / 128, Nqkv / 128), dim3(256), 0, stream>>>(Xb, WqT, b_qkv, Qb, Kb, Vt);
    attn_kernel<<<dim3(NITEMS), dim3(256), 0, stream>>>(Qb, Kb, Vt, An, cnt);
    proj_gemm_kernel<<<dim3(Mc / 128, Dc / 128), dim3(256), 0, stream>>>(An, WpT, b_proj, out);
}

// Round 4
// 271.049 us; speedup vs baseline: 1.1436x; 1.1436x over previous
//
#include <hip/hip_runtime.h>
#include <hip/hip_bf16.h>
#include <cstdint>
#include <cstddef>

// ---------------------------------------------------------------------------
// CausalSelfAttention: x[2,4096,768] fp32, W_qkv[768,2304], b_qkv, W_proj[768,768], b_proj
// bf16 MFMA. All staging via __builtin_amdgcn_global_load_lds(16B) with
// XOR-swizzled source chunks (LDS dest is wave-contiguous => no padding; the
// swizzle c^=row&7 makes fragment reads bank-conflict-free instead).
// Attention: persistent 4-wave blocks + atomic queue; P stays in registers
// via mfma_16x16x16bf16_1k (S^T C-layout == PV B-operand layout).
// R4 lesson: never hold staging loads in VGPRs across compute (spills).
// R6 lesson: LDS staging is mandatory for 4-wave-reused operands.
// R7 lesson: dbuf + counted vmcnt prefetch = NEUTRAL (TLP already hides it).
// R8 lesson: removing the mid-tile barrier = REGRESSION. Lockstep is right.
// R9 lesson: 128-key tiles = REGRESSION (VGPR 148, occupancy 16->11).
// R10 (this round): occupancy is the lever, via MORE BLOCKS not bigger ones.
// Items shrink 128->64 Q rows (16 rows/wave): NITEMS 768->1536 = 6 blocks/CU
// (was 3), per-wave regs halve (sc/o/pb/lp/qf), VGPR ~90 -> 24 waves/CU.
// Staging doubles (FETCH +90MB, fine at 12% HBM); masked waste HALVES.
// Also: czero-hoisted QK first K-step (kills 32 v_mov/tile).
// ---------------------------------------------------------------------------

typedef __attribute__((ext_vector_type(8))) short bf16x8;   // 8 bf16 = 4 VGPRs
typedef __attribute__((ext_vector_type(4))) short bf16x4;   // 4 bf16 = 2 VGPRs
typedef __attribute__((ext_vector_type(4))) float f32x4;

#define MFMA16(a, b, c)   __builtin_amdgcn_mfma_f32_16x16x32_bf16((a), (b), (c), 0, 0, 0)
#define MFMA16K(a, b, c)  __builtin_amdgcn_mfma_f32_16x16x16bf16_1k((a), (b), (c), 0, 0, 0)

static constexpr int Bc = 2, Tc = 4096, Dc = 768, Hc = 12, DKc = 64;
static constexpr int BHc = Bc * Hc;      // 24
static constexpr int Mc = Bc * Tc;       // 8192
static constexpr int Nqkv = 3 * Dc;      // 2304
static constexpr int NQB64 = Tc / 64;    // 64 Q-blocks (64 rows each) per bh
static constexpr unsigned int NITEMS = BHc * NQB64;  // 1536 work items

__device__ __forceinline__ unsigned short f2bf(float f) {
    union { float f; unsigned int i; } c; c.f = f;
    unsigned int x = c.i;
    return (unsigned short)((x + 0x7fffu + ((x >> 16) & 1u)) >> 16); // RNE
}
__device__ __forceinline__ unsigned int pkbf(float a, float b) {
    __hip_bfloat162 h = __float22bfloat162_rn(make_float2(a, b));   // v_cvt_pk_bf16_f32
    union { __hip_bfloat162 h; unsigned int u; } c; c.h = h;
    return c.u;
}
// async global->LDS, 16B per lane; LDS dest = wave-uniform base + lane*16
__device__ __forceinline__ void glds16(const unsigned short* g, unsigned short* l) {
    __builtin_amdgcn_global_load_lds(
        (const __attribute__((address_space(1))) unsigned int*)g,
        (__attribute__((address_space(3))) unsigned int*)l, 16, 0, 0);
}

// ---------------------------------------------------------------------------
// x fp32 -> bf16, flat copy.
// ---------------------------------------------------------------------------
__global__ __launch_bounds__(256)
void xconv_kernel(const float* __restrict__ X, unsigned short* __restrict__ Xb) {
    size_t i = ((size_t)blockIdx.x * 256 + threadIdx.x) * 8;
    float4 a = *(const float4*)(X + i);
    float4 b = *(const float4*)(X + i + 4);
    uint4 o;
    o.x = pkbf(a.x, a.y); o.y = pkbf(a.z, a.w);
    o.z = pkbf(b.x, b.y); o.w = pkbf(b.z, b.w);
    *(uint4*)(Xb + i) = o;
}

// ---------------------------------------------------------------------------
// W [K][N] fp32 -> WT [N][K] bf16.  grid (K/64, N/64), 256 thr.
// ---------------------------------------------------------------------------
__global__ __launch_bounds__(256)
void wtrans_kernel(const float* __restrict__ W, unsigned short* __restrict__ WT,
                   int K, int N) {
    __shared__ __align__(16) unsigned short tile[64 * 72];
    const int k0 = blockIdx.x * 64;
    const int n0 = blockIdx.y * 64;
    const int tid = threadIdx.x;
#pragma unroll
    for (int it = 0; it < 4; ++it) {
        int s = tid + it * 256;
        int r = s >> 4, g = s & 15;
        float4 v = *(const float4*)(W + (size_t)(k0 + r) * N + n0 + g * 4);
        ushort4 u;
        u.x = f2bf(v.x); u.y = f2bf(v.y); u.z = f2bf(v.z); u.w = f2bf(v.w);
        *(ushort4*)(tile + r * 72 + g * 4) = u;
    }
    __syncthreads();
#pragma unroll
    for (int it = 0; it < 2; ++it) {
        int s = tid + it * 256;
        int n = s >> 3, g = s & 7;
        unsigned int p0 = (unsigned int)tile[(g * 8 + 0) * 72 + n] |
                          ((unsigned int)tile[(g * 8 + 1) * 72 + n] << 16);
        unsigned int p1 = (unsigned int)tile[(g * 8 + 2) * 72 + n] |
                          ((unsigned int)tile[(g * 8 + 3) * 72 + n] << 16);
        unsigned int p2 = (unsigned int)tile[(g * 8 + 4) * 72 + n] |
                          ((unsigned int)tile[(g * 8 + 5) * 72 + n] << 16);
        unsigned int p3 = (unsigned int)tile[(g * 8 + 6) * 72 + n] |
                          ((unsigned int)tile[(g * 8 + 7) * 72 + n] << 16);
        uint4 o; o.x = p0; o.y = p1; o.z = p2; o.w = p3;
        *(uint4*)(WT + (size_t)(n0 + n) * K + k0 + g * 8) = o;
    }
}

// ---------------------------------------------------------------------------
// QKV GEMM: Xb[8192][768] bf16 x WqT[2304][768] bf16 (+bias) -> Q/K [bh][t][dk],
// V transposed to Vt [bh][dk][t]. Q pre-scaled by 0.125*log2(e).
// BK=64, global_load_lds staging, XOR-swizzled chunks. grid (64,18).
// ---------------------------------------------------------------------------
__global__ __launch_bounds__(256)
void qkv_gemm_kernel(const unsigned short* __restrict__ Xb,
                     const unsigned short* __restrict__ WT,
                     const float* __restrict__ bias,
                     unsigned short* __restrict__ Qb, unsigned short* __restrict__ Kb,
                     unsigned short* __restrict__ Vt) {
    __shared__ __align__(16) unsigned short As[128 * 64];  // [row][64K], swizzled
    __shared__ __align__(16) unsigned short Bs[128 * 64];
    const int tid = threadIdx.x;
    const int wave = tid >> 6, lane = tid & 63;
    const int quad = lane >> 4, l15 = lane & 15;
    const int wr = wave >> 1, wc = wave & 1;
    const int r0 = blockIdx.x * 128, c0 = blockIdx.y * 128;
    const int sw = l15 & 7;   // fragment-read swizzle key (row&7 == l15&7)

    f32x4 acc[4][4];
#pragma unroll
    for (int i = 0; i < 4; ++i)
#pragma unroll
        for (int j = 0; j < 4; ++j) acc[i][j] = (f32x4){0.f, 0.f, 0.f, 0.f};

    for (int k0 = 0; k0 < Dc; k0 += 64) {
#pragma unroll
        for (int it = 0; it < 4; ++it) {      // stage 128x64 A and B tiles
            int idx = it * 256 + tid;
            int r = idx >> 3, c = idx & 7;
            int cg = c ^ (r & 7);             // LDS slot c holds global chunk cg
            glds16(Xb + (size_t)(r0 + r) * Dc + k0 + cg * 8, As + idx * 8);
            glds16(WT + (size_t)(c0 + r) * Dc + k0 + cg * 8, Bs + idx * 8);
        }
        __syncthreads();
#pragma unroll
        for (int f = 0; f < 2; ++f) {
            bf16x8 af[4], bfr[4];
#pragma unroll
            for (int mt = 0; mt < 4; ++mt)
                af[mt] = *(const bf16x8*)(As + (wr * 64 + mt * 16 + l15) * 64 +
                                          (((f * 4 + quad) ^ sw) * 8));
#pragma unroll
            for (int nt = 0; nt < 4; ++nt)
                bfr[nt] = *(const bf16x8*)(Bs + (wc * 64 + nt * 16 + l15) * 64 +
                                           (((f * 4 + quad) ^ sw) * 8));
#pragma unroll
            for (int mt = 0; mt < 4; ++mt)
#pragma unroll
                for (int nt = 0; nt < 4; ++nt)
                    acc[mt][nt] = MFMA16(af[mt], bfr[nt], acc[mt][nt]);
        }
        __syncthreads();
    }

    const int part = c0 / Dc;
    const int cbase = c0 - part * Dc;
    const float scale = (part == 0) ? 0.125f * 1.4426950408889634f : 1.0f;
    float bv[4];
#pragma unroll
    for (int nt = 0; nt < 4; ++nt) bv[nt] = bias[c0 + wc * 64 + nt * 16 + l15];

    if (part < 2) {
        unsigned short* dstbuf = (part == 0) ? Qb : Kb;
#pragma unroll
        for (int mt = 0; mt < 4; ++mt)
#pragma unroll
            for (int reg = 0; reg < 4; ++reg) {
                int gr = r0 + wr * 64 + mt * 16 + quad * 4 + reg;
                int b = gr >> 12, t = gr & 4095;
#pragma unroll
                for (int nt = 0; nt < 4; ++nt) {
                    int cc = cbase + wc * 64 + nt * 16 + l15;
                    int h = cc >> 6, dk = cc & 63;
                    float v = (acc[mt][nt][reg] + bv[nt]) * scale;
                    dstbuf[((size_t)(b * Hc + h) * Tc + t) * DKc + dk] = f2bf(v);
                }
            }
    } else {
        // V: write transposed [bh][dk][t]
#pragma unroll
        for (int mt = 0; mt < 4; ++mt)
#pragma unroll
            for (int reg = 0; reg < 4; ++reg) {
                int gr = r0 + wr * 64 + mt * 16 + quad * 4 + reg;
                int b = gr >> 12, t = gr & 4095;
#pragma unroll
                for (int nt = 0; nt < 4; ++nt) {
                    int cc = cbase + wc * 64 + nt * 16 + l15;
                    int h = cc >> 6, dk = cc & 63;
                    float v = acc[mt][nt][reg] + bv[nt];
                    Vt[((size_t)(b * Hc + h) * DKc + dk) * Tc + t] = f2bf(v);
                }
            }
    }
}

// ---------------------------------------------------------------------------
// Flash attention: persistent 4-wave blocks + atomic queue, 1536 items of
// (bh, 64 Q rows), longest first. Each wave owns 16 rows (q = i0+wave*16+l15).
// R6-proven lockstep per 64-key tile:
//   global_load_lds K[key][dk] and V^T[dk][key] (swizzled chunks); barrier;
//   frags -> regs (kf b128, vf b64, swizzle-indexed, conflict-free); barrier
//   EARLY so waves finishing compute can stage the next tile;
//   S^T = MFMA16(kf,qf) C-layout (key=16mt+quad*4+reg, q=l15), first K-step
//   folds czero (no per-tile acc zero-init);
//   fixed-max softmax: exp2 (log2e folded into Q), per-lane partials;
//   P packed bf16x4 in-register == B operand of mfma_16x16x16bf16_1k;
//   O^T += V^T P^T, C-layout -> per-lane scalar 1/l, direct store.
// 6 blocks/CU resident (VGPR ~90, LDS 16.9KB) = 24 waves/CU for barrier-idle
// coverage; this is the occupancy R9 destroyed and R7/R8 couldn't fake.
// ---------------------------------------------------------------------------
__global__ __launch_bounds__(256)
void attn_kernel(const unsigned short* __restrict__ Qb,
                 const unsigned short* __restrict__ Kb,
                 const unsigned short* __restrict__ Vt,
                 unsigned short* __restrict__ attn,
                 unsigned int* __restrict__ counter) {
    __shared__ __align__(16) unsigned short Ks[64 * 64];   // [key][dk] swizzled
    __shared__ __align__(16) unsigned short Vs[64 * 64];   // [dk][key] swizzled
    __shared__ unsigned int s_w;
    const int tid = threadIdx.x;
    const int wave = tid >> 6, lane = tid & 63;
    const int quad = lane >> 4, l15 = lane & 15;
    const int sw = l15 & 7;
    const f32x4 czero = (f32x4){0.f, 0.f, 0.f, 0.f};

    for (;;) {
        if (tid == 0) s_w = atomicAdd(counter, 1u);
        __syncthreads();
        const unsigned int w = s_w;
        if (w >= NITEMS) break;
        const int bh = (int)(w % (unsigned)BHc);
        const int i0 = (NQB64 - 1 - (int)(w / (unsigned)BHc)) * 64;  // longest first
        const unsigned short* Qp = Qb + (size_t)bh * Tc * DKc;
        const unsigned short* Kp = Kb + (size_t)bh * Tc * DKc;
        const unsigned short* Vp = Vt + (size_t)bh * DKc * Tc;

        // Q fragments for this wave's 16 rows (pre-scaled 0.125*log2e)
        bf16x8 qf[2];
#pragma unroll
        for (int f = 0; f < 2; ++f)
            qf[f] = *(const bf16x8*)(Qp +
                (size_t)(i0 + wave * 16 + l15) * DKc + f * 32 + quad * 8);

        f32x4 lp = (f32x4){0.f, 0.f, 0.f, 0.f};
        f32x4 o[4];
#pragma unroll
        for (int d = 0; d < 4; ++d) o[d] = (f32x4){0.f, 0.f, 0.f, 0.f};

        const int jmax = i0 >> 6;                          // tiles 0..jmax
        for (int jt = 0; jt <= jmax; ++jt) {
            const int j0 = jt * 64;
#pragma unroll
            for (int it = 0; it < 2; ++it) {               // async staging, swizzled
                int idx = it * 256 + tid;
                int r = idx >> 3, c = idx & 7;
                int cg = c ^ (r & 7);
                glds16(Kp + (size_t)(j0 + r) * DKc + cg * 8, Ks + idx * 8);
                glds16(Vp + (size_t)r * Tc + j0 + cg * 8, Vs + idx * 8);
            }
            __syncthreads();

            // fragments -> regs; then barrier EARLY so next staging can begin
            bf16x8 kf[2][4];
            bf16x4 vf[4][4];
#pragma unroll
            for (int f = 0; f < 2; ++f)
#pragma unroll
                for (int mt = 0; mt < 4; ++mt)
                    kf[f][mt] = *(const bf16x8*)(Ks + (mt * 16 + l15) * 64 +
                                                 (((f * 4 + quad) ^ sw) * 8));
#pragma unroll
            for (int d = 0; d < 4; ++d)
#pragma unroll
                for (int mt = 0; mt < 4; ++mt) {
                    int g8 = mt * 4 + quad;
                    vf[d][mt] = *(const bf16x4*)(Vs + (d * 16 + l15) * 64 +
                                                 (((g8 >> 1) ^ sw) * 8) + (g8 & 1) * 4);
                }
            asm volatile("s_waitcnt lgkmcnt(0)" ::: "memory");
            __builtin_amdgcn_s_barrier();

            // S^T: C-layout key=16mt+quad*4+reg, q=l15; czero folds init
            f32x4 sc[4];
            __builtin_amdgcn_s_setprio(1);
#pragma unroll
            for (int mt = 0; mt < 4; ++mt) {
                sc[mt] = MFMA16(kf[0][mt], qf[0], czero);
                sc[mt] = MFMA16(kf[1][mt], qf[1], sc[mt]);
            }
            __builtin_amdgcn_s_setprio(0);

            if (jt == jmax) {                              // diagonal tile
                int qrow = wave * 16 + l15;
#pragma unroll
                for (int mt = 0; mt < 4; ++mt)
#pragma unroll
                    for (int reg = 0; reg < 4; ++reg)
                        if (mt * 16 + quad * 4 + reg > qrow)
                            sc[mt][reg] = -1e30f;
            }

            // exp2 + partial row sums + pack P^T (B-operand, in-register)
            union { uint2 u; bf16x4 v; } pb[4];
#pragma unroll
            for (int mt = 0; mt < 4; ++mt) {
#pragma unroll
                for (int reg = 0; reg < 4; ++reg)
                    sc[mt][reg] = __builtin_amdgcn_exp2f(sc[mt][reg]);
                lp += sc[mt];
                pb[mt].u.x = pkbf(sc[mt][0], sc[mt][1]);
                pb[mt].u.y = pkbf(sc[mt][2], sc[mt][3]);
            }

            // O^T += V^T P^T
            __builtin_amdgcn_s_setprio(1);
#pragma unroll
            for (int mt = 0; mt < 4; ++mt)
#pragma unroll
                for (int d = 0; d < 4; ++d)
                    o[d] = MFMA16K(vf[d][mt], pb[mt].v, o[d]);
            __builtin_amdgcn_s_setprio(0);
        }

        // normalize + store: lane owns q = i0+wave*16+l15 for all o
        const int b = bh / Hc, h = bh % Hc;
        float ls = lp[0] + lp[1] + lp[2] + lp[3];
        ls += __shfl_xor(ls, 16);
        ls += __shfl_xor(ls, 32);
        float li = 1.0f / ls;
        int t = i0 + wave * 16 + l15;
        unsigned short* dst = attn + (size_t)(b * Tc + t) * Dc + h * 64;
#pragma unroll
        for (int d = 0; d < 4; ++d) {
            uint2 u;
            u.x = pkbf(o[d][0] * li, o[d][1] * li);
            u.y = pkbf(o[d][2] * li, o[d][3] * li);
            *(uint2*)(dst + d * 16 + quad * 4) = u;
        }
    }
}

// ---------------------------------------------------------------------------
// Proj GEMM: A[8192][768] bf16 x WpT[768][768] bf16 (+bias) -> out fp32
// BK=64, global_load_lds staging, XOR-swizzled. grid (64, 6), 256 thr.
// ---------------------------------------------------------------------------
__global__ __launch_bounds__(256)
void proj_gemm_kernel(const unsigned short* __restrict__ A,
                      const unsigned short* __restrict__ WT,
                      const float* __restrict__ bias, float* __restrict__ out) {
    __shared__ __align__(16) unsigned short As[128 * 64];
    __shared__ __align__(16) unsigned short Bs[128 * 64];
    const int tid = threadIdx.x;
    const int wave = tid >> 6, lane = tid & 63;
    const int quad = lane >> 4, l15 = lane & 15;
    const int wr = wave >> 1, wc = wave & 1;
    const int r0 = blockIdx.x * 128, c0 = blockIdx.y * 128;
    const int sw = l15 & 7;

    f32x4 acc[4][4];
#pragma unroll
    for (int i = 0; i < 4; ++i)
#pragma unroll
        for (int j = 0; j < 4; ++j) acc[i][j] = (f32x4){0.f, 0.f, 0.f, 0.f};

    for (int k0 = 0; k0 < Dc; k0 += 64) {
#pragma unroll
        for (int it = 0; it < 4; ++it) {
            int idx = it * 256 + tid;
            int r = idx >> 3, c = idx & 7;
            int cg = c ^ (r & 7);
            glds16(A + (size_t)(r0 + r) * Dc + k0 + cg * 8, As + idx * 8);
            glds16(WT + (size_t)(c0 + r) * Dc + k0 + cg * 8, Bs + idx * 8);
        }
        __syncthreads();
#pragma unroll
        for (int f = 0; f < 2; ++f) {
            bf16x8 af[4], bfr[4];
#pragma unroll
            for (int mt = 0; mt < 4; ++mt)
                af[mt] = *(const bf16x8*)(As + (wr * 64 + mt * 16 + l15) * 64 +
                                          (((f * 4 + quad) ^ sw) * 8));
#pragma unroll
            for (int nt = 0; nt < 4; ++nt)
                bfr[nt] = *(const bf16x8*)(Bs + (wc * 64 + nt * 16 + l15) * 64 +
                                           (((f * 4 + quad) ^ sw) * 8));
#pragma unroll
            for (int mt = 0; mt < 4; ++mt)
#pragma unroll
                for (int nt = 0; nt < 4; ++nt)
                    acc[mt][nt] = MFMA16(af[mt], bfr[nt], acc[mt][nt]);
        }
        __syncthreads();
    }

    float bv[4];
#pragma unroll
    for (int nt = 0; nt < 4; ++nt) bv[nt] = bias[c0 + wc * 64 + nt * 16 + l15];
#pragma unroll
    for (int mt = 0; mt < 4; ++mt)
#pragma unroll
        for (int reg = 0; reg < 4; ++reg) {
            int gr = r0 + wr * 64 + mt * 16 + quad * 4 + reg;
#pragma unroll
            for (int nt = 0; nt < 4; ++nt) {
                int gc = c0 + wc * 64 + nt * 16 + l15;
                out[(size_t)gr * Dc + gc] = acc[mt][nt][reg] + bv[nt];
            }
        }
}

// ---------------------------------------------------------------------------
extern "C" void kernel_launch(void* const* d_in, const int* in_sizes, int n_in,
                              void* d_out, int out_size, void* d_ws, size_t ws_size,
                              hipStream_t stream) {
    const float* x      = (const float*)d_in[0];
    const float* W_qkv  = (const float*)d_in[1];
    const float* b_qkv  = (const float*)d_in[2];
    const float* W_proj = (const float*)d_in[3];
    const float* b_proj = (const float*)d_in[4];
    float* out = (float*)d_out;

    char* ws = (char*)d_ws;
    size_t off = 0;
    auto take = [&](size_t bytes) -> char* {
        char* p = ws + off;
        off += (bytes + 255) & ~(size_t)255;
        return p;
    };
    unsigned int*   cnt = (unsigned int*)take(256);
    unsigned short* WqT = (unsigned short*)take((size_t)Nqkv * Dc * 2);  // [2304][768]
    unsigned short* WpT = (unsigned short*)take((size_t)Dc * Dc * 2);    // [768][768]
    unsigned short* Qb  = (unsigned short*)take((size_t)BHc * Tc * DKc * 2);
    unsigned short* Kb  = (unsigned short*)take((size_t)BHc * Tc * DKc * 2);
    unsigned short* Vt  = (unsigned short*)take((size_t)BHc * Tc * DKc * 2);
    unsigned short* Xb  = (unsigned short*)take((size_t)Mc * Dc * 2);
    unsigned short* An  = Xb;  // alias: Xb dead after qkv_gemm

    hipMemsetAsync(cnt, 0, sizeof(unsigned int), stream);
    xconv_kernel<<<dim3((Mc * Dc) / (256 * 8)), dim3(256), 0, stream>>>(x, Xb);
    wtrans_kernel<<<dim3(Dc / 64, Nqkv / 64), dim3(256), 0, stream>>>(W_qkv, WqT, Dc, Nqkv);
    wtrans_kernel<<<dim3(Dc / 64, Dc / 64), dim3(256), 0, stream>>>(W_proj, WpT, Dc, Dc);
    qkv_gemm_kernel<<<dim3(Mc / 128, Nqkv / 128), dim3(256), 0, stream>>>(Xb, WqT, b_qkv, Qb, Kb, Vt);
    attn_kernel<<<dim3(NITEMS), dim3(256), 0, stream>>>(Qb, Kb, Vt, An, cnt);
    proj_gemm_kernel<<<dim3(Mc / 128, Dc / 128), dim3(256), 0, stream>>>(An, WpT, b_proj, out);
}

// Round 5
// 253.616 us; speedup vs baseline: 1.2222x; 1.0687x over previous
//
#include <hip/hip_runtime.h>
#include <hip/hip_bf16.h>
#include <cstdint>
#include <cstddef>

// ---------------------------------------------------------------------------
// CausalSelfAttention: x[2,4096,768] fp32, W_qkv[768,2304], b_qkv, W_proj[768,768], b_proj
// bf16 MFMA. All staging via __builtin_amdgcn_global_load_lds(16B) with
// XOR-swizzled source chunks (LDS dest is wave-contiguous => no padding; the
// swizzle c^=row&7 makes fragment reads bank-conflict-free instead).
// Attention: persistent 4-wave blocks + atomic queue; P stays in registers
// via mfma_16x16x16bf16_1k (S^T C-layout == PV B-operand layout).
// R4 lesson: never hold staging loads in VGPRs across compute (spills).
// R6 lesson: LDS staging is mandatory for 4-wave-reused operands.
// R7 lesson: dbuf + counted vmcnt prefetch = NEUTRAL (TLP already hides it).
// R8 lesson: removing the mid-tile barrier = REGRESSION. Lockstep is right.
// R9 lesson: 128-key tiles = REGRESSION (VGPR 148, occupancy 16->11).
// R10 lesson: 64-row items = REGRESSION (staging/LDS overhead doubles; the
// 128-row/64-key R0 shape is a schedule/occupancy local optimum).
// R11 (this round): VALU diet inside the EXACT R0 structure:
//   (a) czero-folded QK C-operand kills 32 v_mov/tile;
//   (b) row-sums via MFMA16K(ones, P) on the 26%-busy matrix pipe kills
//       32 v_add_f32/tile + the epilogue shfl reduce (A==1 => C = colsum(B)
//       = rowsum(P) for q=l15, identical across regs/quads).
// Plus: proj_gemm 128x64 tiles (768 blocks = 3/CU, no tail) and merged
// wtrans launch. Predicted attn 124 -> ~112.
// ---------------------------------------------------------------------------

typedef __attribute__((ext_vector_type(8))) short bf16x8;   // 8 bf16 = 4 VGPRs
typedef __attribute__((ext_vector_type(4))) short bf16x4;   // 4 bf16 = 2 VGPRs
typedef __attribute__((ext_vector_type(4))) float f32x4;

#define MFMA16(a, b, c)   __builtin_amdgcn_mfma_f32_16x16x32_bf16((a), (b), (c), 0, 0, 0)
#define MFMA16K(a, b, c)  __builtin_amdgcn_mfma_f32_16x16x16bf16_1k((a), (b), (c), 0, 0, 0)

static constexpr int Bc = 2, Tc = 4096, Dc = 768, Hc = 12, DKc = 64;
static constexpr int BHc = Bc * Hc;      // 24
static constexpr int Mc = Bc * Tc;       // 8192
static constexpr int Nqkv = 3 * Dc;      // 2304
static constexpr int NQBLK = Tc / 128;   // 32 Q-blocks per bh
static constexpr unsigned int NITEMS = BHc * NQBLK;  // 768 work items

__device__ __forceinline__ unsigned short f2bf(float f) {
    union { float f; unsigned int i; } c; c.f = f;
    unsigned int x = c.i;
    return (unsigned short)((x + 0x7fffu + ((x >> 16) & 1u)) >> 16); // RNE
}
__device__ __forceinline__ unsigned int pkbf(float a, float b) {
    __hip_bfloat162 h = __float22bfloat162_rn(make_float2(a, b));   // v_cvt_pk_bf16_f32
    union { __hip_bfloat162 h; unsigned int u; } c; c.h = h;
    return c.u;
}
// async global->LDS, 16B per lane; LDS dest = wave-uniform base + lane*16
__device__ __forceinline__ void glds16(const unsigned short* g, unsigned short* l) {
    __builtin_amdgcn_global_load_lds(
        (const __attribute__((address_space(1))) unsigned int*)g,
        (__attribute__((address_space(3))) unsigned int*)l, 16, 0, 0);
}

// ---------------------------------------------------------------------------
// x fp32 -> bf16, flat copy.
// ---------------------------------------------------------------------------
__global__ __launch_bounds__(256)
void xconv_kernel(const float* __restrict__ X, unsigned short* __restrict__ Xb) {
    size_t i = ((size_t)blockIdx.x * 256 + threadIdx.x) * 8;
    float4 a = *(const float4*)(X + i);
    float4 b = *(const float4*)(X + i + 4);
    uint4 o;
    o.x = pkbf(a.x, a.y); o.y = pkbf(a.z, a.w);
    o.z = pkbf(b.x, b.y); o.w = pkbf(b.z, b.w);
    *(uint4*)(Xb + i) = o;
}

// ---------------------------------------------------------------------------
// W [768][N] fp32 -> WT [N][768] bf16, both weight matrices in ONE launch.
// grid (12, 48): y<36 -> W_qkv (N=2304), else W_proj (N=768). 256 thr.
// ---------------------------------------------------------------------------
__global__ __launch_bounds__(256)
void wtrans_kernel(const float* __restrict__ Wq, const float* __restrict__ Wp,
                   unsigned short* __restrict__ WqT, unsigned short* __restrict__ WpT) {
    __shared__ __align__(16) unsigned short tile[64 * 72];
    const int k0 = blockIdx.x * 64;
    const int yb = blockIdx.y;
    const float* W;
    unsigned short* WT;
    int N, n0;
    if (yb < 36) { W = Wq; WT = WqT; N = Nqkv; n0 = yb * 64; }
    else         { W = Wp; WT = WpT; N = Dc;   n0 = (yb - 36) * 64; }
    const int tid = threadIdx.x;
#pragma unroll
    for (int it = 0; it < 4; ++it) {
        int s = tid + it * 256;
        int r = s >> 4, g = s & 15;
        float4 v = *(const float4*)(W + (size_t)(k0 + r) * N + n0 + g * 4);
        ushort4 u;
        u.x = f2bf(v.x); u.y = f2bf(v.y); u.z = f2bf(v.z); u.w = f2bf(v.w);
        *(ushort4*)(tile + r * 72 + g * 4) = u;
    }
    __syncthreads();
#pragma unroll
    for (int it = 0; it < 2; ++it) {
        int s = tid + it * 256;
        int n = s >> 3, g = s & 7;
        unsigned int p0 = (unsigned int)tile[(g * 8 + 0) * 72 + n] |
                          ((unsigned int)tile[(g * 8 + 1) * 72 + n] << 16);
        unsigned int p1 = (unsigned int)tile[(g * 8 + 2) * 72 + n] |
                          ((unsigned int)tile[(g * 8 + 3) * 72 + n] << 16);
        unsigned int p2 = (unsigned int)tile[(g * 8 + 4) * 72 + n] |
                          ((unsigned int)tile[(g * 8 + 5) * 72 + n] << 16);
        unsigned int p3 = (unsigned int)tile[(g * 8 + 6) * 72 + n] |
                          ((unsigned int)tile[(g * 8 + 7) * 72 + n] << 16);
        uint4 o; o.x = p0; o.y = p1; o.z = p2; o.w = p3;
        *(uint4*)(WT + (size_t)(n0 + n) * Dc + k0 + g * 8) = o;
    }
}

// ---------------------------------------------------------------------------
// QKV GEMM: Xb[8192][768] bf16 x WqT[2304][768] bf16 (+bias) -> Q/K [bh][t][dk],
// V transposed to Vt [bh][dk][t]. Q pre-scaled by 0.125*log2(e).
// BK=64, global_load_lds staging, XOR-swizzled chunks. grid (64,18).
// ---------------------------------------------------------------------------
__global__ __launch_bounds__(256)
void qkv_gemm_kernel(const unsigned short* __restrict__ Xb,
                     const unsigned short* __restrict__ WT,
                     const float* __restrict__ bias,
                     unsigned short* __restrict__ Qb, unsigned short* __restrict__ Kb,
                     unsigned short* __restrict__ Vt) {
    __shared__ __align__(16) unsigned short As[128 * 64];  // [row][64K], swizzled
    __shared__ __align__(16) unsigned short Bs[128 * 64];
    const int tid = threadIdx.x;
    const int wave = tid >> 6, lane = tid & 63;
    const int quad = lane >> 4, l15 = lane & 15;
    const int wr = wave >> 1, wc = wave & 1;
    const int r0 = blockIdx.x * 128, c0 = blockIdx.y * 128;
    const int sw = l15 & 7;   // fragment-read swizzle key (row&7 == l15&7)

    f32x4 acc[4][4];
#pragma unroll
    for (int i = 0; i < 4; ++i)
#pragma unroll
        for (int j = 0; j < 4; ++j) acc[i][j] = (f32x4){0.f, 0.f, 0.f, 0.f};

    for (int k0 = 0; k0 < Dc; k0 += 64) {
#pragma unroll
        for (int it = 0; it < 4; ++it) {      // stage 128x64 A and B tiles
            int idx = it * 256 + tid;
            int r = idx >> 3, c = idx & 7;
            int cg = c ^ (r & 7);             // LDS slot c holds global chunk cg
            glds16(Xb + (size_t)(r0 + r) * Dc + k0 + cg * 8, As + idx * 8);
            glds16(WT + (size_t)(c0 + r) * Dc + k0 + cg * 8, Bs + idx * 8);
        }
        __syncthreads();
#pragma unroll
        for (int f = 0; f < 2; ++f) {
            bf16x8 af[4], bfr[4];
#pragma unroll
            for (int mt = 0; mt < 4; ++mt)
                af[mt] = *(const bf16x8*)(As + (wr * 64 + mt * 16 + l15) * 64 +
                                          (((f * 4 + quad) ^ sw) * 8));
#pragma unroll
            for (int nt = 0; nt < 4; ++nt)
                bfr[nt] = *(const bf16x8*)(Bs + (wc * 64 + nt * 16 + l15) * 64 +
                                           (((f * 4 + quad) ^ sw) * 8));
#pragma unroll
            for (int mt = 0; mt < 4; ++mt)
#pragma unroll
                for (int nt = 0; nt < 4; ++nt)
                    acc[mt][nt] = MFMA16(af[mt], bfr[nt], acc[mt][nt]);
        }
        __syncthreads();
    }

    const int part = c0 / Dc;
    const int cbase = c0 - part * Dc;
    const float scale = (part == 0) ? 0.125f * 1.4426950408889634f : 1.0f;
    float bv[4];
#pragma unroll
    for (int nt = 0; nt < 4; ++nt) bv[nt] = bias[c0 + wc * 64 + nt * 16 + l15];

    if (part < 2) {
        unsigned short* dstbuf = (part == 0) ? Qb : Kb;
#pragma unroll
        for (int mt = 0; mt < 4; ++mt)
#pragma unroll
            for (int reg = 0; reg < 4; ++reg) {
                int gr = r0 + wr * 64 + mt * 16 + quad * 4 + reg;
                int b = gr >> 12, t = gr & 4095;
#pragma unroll
                for (int nt = 0; nt < 4; ++nt) {
                    int cc = cbase + wc * 64 + nt * 16 + l15;
                    int h = cc >> 6, dk = cc & 63;
                    float v = (acc[mt][nt][reg] + bv[nt]) * scale;
                    dstbuf[((size_t)(b * Hc + h) * Tc + t) * DKc + dk] = f2bf(v);
                }
            }
    } else {
        // V: write transposed [bh][dk][t]
#pragma unroll
        for (int mt = 0; mt < 4; ++mt)
#pragma unroll
            for (int reg = 0; reg < 4; ++reg) {
                int gr = r0 + wr * 64 + mt * 16 + quad * 4 + reg;
                int b = gr >> 12, t = gr & 4095;
#pragma unroll
                for (int nt = 0; nt < 4; ++nt) {
                    int cc = cbase + wc * 64 + nt * 16 + l15;
                    int h = cc >> 6, dk = cc & 63;
                    float v = acc[mt][nt][reg] + bv[nt];
                    Vt[((size_t)(b * Hc + h) * DKc + dk) * Tc + t] = f2bf(v);
                }
            }
    }
}

// ---------------------------------------------------------------------------
// Flash attention: persistent 4-wave blocks + atomic queue, 768 items of
// (bh, 128 Q rows), longest first. EXACT R0 lockstep structure; per tile:
//   global_load_lds K[key][dk] and V^T[dk][key] (swizzled chunks); barrier;
//   frags -> regs (kf b128, vf b64, swizzle-indexed, conflict-free); barrier
//   EARLY so waves finishing compute can stage the next tile;
//   S^T = MFMA16(kf,qf) C-layout (key=16mt+quad*4+reg, q=l15) with czero as
//   the first K-step C operand (no per-tile acc zero-init);
//   fixed-max softmax: exp2 (log2e folded into Q);
//   P packed bf16x4 in-register == B operand of mfma_16x16x16bf16_1k;
//   row-sums lsum += MFMA16K(ones, P) on the matrix pipe (A==1 => C =
//   colsum(B) = rowsum(P) for q=l15, identical in all regs/quads — no
//   VALU adds, no epilogue shuffle);
//   O^T += V^T P^T, C-layout -> per-lane scalar 1/lsum[0], direct store.
// ---------------------------------------------------------------------------
__global__ __launch_bounds__(256)
void attn_kernel(const unsigned short* __restrict__ Qb,
                 const unsigned short* __restrict__ Kb,
                 const unsigned short* __restrict__ Vt,
                 unsigned short* __restrict__ attn,
                 unsigned int* __restrict__ counter) {
    __shared__ __align__(16) unsigned short Ks[64 * 64];   // [key][dk] swizzled
    __shared__ __align__(16) unsigned short Vs[64 * 64];   // [dk][key] swizzled
    __shared__ unsigned int s_w;
    const int tid = threadIdx.x;
    const int wave = tid >> 6, lane = tid & 63;
    const int quad = lane >> 4, l15 = lane & 15;
    const int sw = l15 & 7;
    const f32x4 czero = (f32x4){0.f, 0.f, 0.f, 0.f};
    const bf16x4 ones = (bf16x4){(short)0x3F80, (short)0x3F80,
                                 (short)0x3F80, (short)0x3F80};  // bf16 1.0 x4

    for (;;) {
        if (tid == 0) s_w = atomicAdd(counter, 1u);
        __syncthreads();
        const unsigned int w = s_w;
        if (w >= NITEMS) break;
        const int bh = (int)(w % (unsigned)BHc);
        const int i0 = (NQBLK - 1 - (int)(w / (unsigned)BHc)) * 128;  // longest first
        const unsigned short* Qp = Qb + (size_t)bh * Tc * DKc;
        const unsigned short* Kp = Kb + (size_t)bh * Tc * DKc;
        const unsigned short* Vp = Vt + (size_t)bh * DKc * Tc;

        // Q fragments for this wave's 32 rows (pre-scaled 0.125*log2e)
        bf16x8 qf[2][2];
#pragma unroll
        for (int qg = 0; qg < 2; ++qg)
#pragma unroll
            for (int f = 0; f < 2; ++f)
                qf[qg][f] = *(const bf16x8*)(Qp +
                    (size_t)(i0 + wave * 32 + qg * 16 + l15) * DKc + f * 32 + quad * 8);

        f32x4 lsum[2] = {czero, czero};
        f32x4 o[2][4];
#pragma unroll
        for (int qg = 0; qg < 2; ++qg)
#pragma unroll
            for (int d = 0; d < 4; ++d) o[qg][d] = (f32x4){0.f, 0.f, 0.f, 0.f};

        const int jmax = (i0 >> 6) + 1;                    // tiles 0..jmax
        for (int jt = 0; jt <= jmax; ++jt) {
            const int j0 = jt * 64;
#pragma unroll
            for (int it = 0; it < 2; ++it) {               // async staging, swizzled
                int idx = it * 256 + tid;
                int r = idx >> 3, c = idx & 7;
                int cg = c ^ (r & 7);
                glds16(Kp + (size_t)(j0 + r) * DKc + cg * 8, Ks + idx * 8);
                glds16(Vp + (size_t)r * Tc + j0 + cg * 8, Vs + idx * 8);
            }
            __syncthreads();

            // fragments -> regs; then barrier EARLY so next staging can begin
            bf16x8 kf[2][4];
            bf16x4 vf[4][4];
#pragma unroll
            for (int f = 0; f < 2; ++f)
#pragma unroll
                for (int mt = 0; mt < 4; ++mt)
                    kf[f][mt] = *(const bf16x8*)(Ks + (mt * 16 + l15) * 64 +
                                                 (((f * 4 + quad) ^ sw) * 8));
#pragma unroll
            for (int d = 0; d < 4; ++d)
#pragma unroll
                for (int mt = 0; mt < 4; ++mt) {
                    int g8 = mt * 4 + quad;
                    vf[d][mt] = *(const bf16x4*)(Vs + (d * 16 + l15) * 64 +
                                                 (((g8 >> 1) ^ sw) * 8) + (g8 & 1) * 4);
                }
            asm volatile("s_waitcnt lgkmcnt(0)" ::: "memory");
            __builtin_amdgcn_s_barrier();

            // S^T: C-layout key=16mt+quad*4+reg, q=l15; czero folds the init
            f32x4 sc[2][4];
#pragma unroll
            for (int mt = 0; mt < 4; ++mt) {
                sc[0][mt] = MFMA16(kf[0][mt], qf[0][0], czero);
                sc[1][mt] = MFMA16(kf[0][mt], qf[1][0], czero);
            }
#pragma unroll
            for (int mt = 0; mt < 4; ++mt) {
                sc[0][mt] = MFMA16(kf[1][mt], qf[0][1], sc[0][mt]);
                sc[1][mt] = MFMA16(kf[1][mt], qf[1][1], sc[1][mt]);
            }

            const int rel = j0 - i0;
            if (jt >= jmax - 1) {                          // diagonal region
#pragma unroll
                for (int qg = 0; qg < 2; ++qg) {
                    int qrow = wave * 32 + qg * 16 + l15;
#pragma unroll
                    for (int mt = 0; mt < 4; ++mt)
#pragma unroll
                        for (int reg = 0; reg < 4; ++reg)
                            if (rel + mt * 16 + quad * 4 + reg > qrow)
                                sc[qg][mt][reg] = -1e30f;
                }
            }

            // exp2 + pack P^T (B-operand, in-register); row sums via MFMA
            union { uint2 u; bf16x4 v; } pb[2][4];
#pragma unroll
            for (int qg = 0; qg < 2; ++qg)
#pragma unroll
                for (int mt = 0; mt < 4; ++mt) {
#pragma unroll
                    for (int reg = 0; reg < 4; ++reg)
                        sc[qg][mt][reg] = __builtin_amdgcn_exp2f(sc[qg][mt][reg]);
                    pb[qg][mt].u.x = pkbf(sc[qg][mt][0], sc[qg][mt][1]);
                    pb[qg][mt].u.y = pkbf(sc[qg][mt][2], sc[qg][mt][3]);
                }

            // lsum += colsum(P^T) (= rowsum for q=l15); O^T += V^T P^T
#pragma unroll
            for (int mt = 0; mt < 4; ++mt) {
                lsum[0] = MFMA16K(ones, pb[0][mt].v, lsum[0]);
                lsum[1] = MFMA16K(ones, pb[1][mt].v, lsum[1]);
#pragma unroll
                for (int d = 0; d < 4; ++d) {
                    o[0][d] = MFMA16K(vf[d][mt], pb[0][mt].v, o[0][d]);
                    o[1][d] = MFMA16K(vf[d][mt], pb[1][mt].v, o[1][d]);
                }
            }
        }

        // normalize + store: lane owns q = i0+wave*32+qg*16+l15 for all o;
        // lsum regs are identical (every C row = the same column sum)
        const int b = bh / Hc, h = bh % Hc;
#pragma unroll
        for (int qg = 0; qg < 2; ++qg) {
            float li = 1.0f / lsum[qg][0];
            int t = i0 + wave * 32 + qg * 16 + l15;
            unsigned short* dst = attn + (size_t)(b * Tc + t) * Dc + h * 64;
#pragma unroll
            for (int d = 0; d < 4; ++d) {
                uint2 u;
                u.x = pkbf(o[qg][d][0] * li, o[qg][d][1] * li);
                u.y = pkbf(o[qg][d][2] * li, o[qg][d][3] * li);
                *(uint2*)(dst + d * 16 + quad * 4) = u;
            }
        }
    }
}

// ---------------------------------------------------------------------------
// Proj GEMM: A[8192][768] bf16 x WpT[768][768] bf16 (+bias) -> out fp32
// 128x64 tiles, BK=64: grid (64,12) = 768 blocks = 3/CU exact (no tail).
// ---------------------------------------------------------------------------
__global__ __launch_bounds__(256)
void proj_gemm_kernel(const unsigned short* __restrict__ A,
                      const unsigned short* __restrict__ WT,
                      const float* __restrict__ bias, float* __restrict__ out) {
    __shared__ __align__(16) unsigned short As[128 * 64];
    __shared__ __align__(16) unsigned short Bs[64 * 64];
    const int tid = threadIdx.x;
    const int wave = tid >> 6, lane = tid & 63;
    const int quad = lane >> 4, l15 = lane & 15;
    const int wr = wave >> 1, wc = wave & 1;
    const int r0 = blockIdx.x * 128, c0 = blockIdx.y * 64;
    const int sw = l15 & 7;

    f32x4 acc[4][2];
#pragma unroll
    for (int i = 0; i < 4; ++i)
#pragma unroll
        for (int j = 0; j < 2; ++j) acc[i][j] = (f32x4){0.f, 0.f, 0.f, 0.f};

    for (int k0 = 0; k0 < Dc; k0 += 64) {
#pragma unroll
        for (int it = 0; it < 4; ++it) {      // A: 128 rows x 8 chunks
            int idx = it * 256 + tid;
            int r = idx >> 3, c = idx & 7;
            glds16(A + (size_t)(r0 + r) * Dc + k0 + ((c ^ (r & 7)) * 8), As + idx * 8);
        }
#pragma unroll
        for (int it = 0; it < 2; ++it) {      // B: 64 rows x 8 chunks
            int idx = it * 256 + tid;
            int r = idx >> 3, c = idx & 7;
            glds16(WT + (size_t)(c0 + r) * Dc + k0 + ((c ^ (r & 7)) * 8), Bs + idx * 8);
        }
        __syncthreads();
#pragma unroll
        for (int f = 0; f < 2; ++f) {
            bf16x8 af[4], bfr[2];
#pragma unroll
            for (int mt = 0; mt < 4; ++mt)
                af[mt] = *(const bf16x8*)(As + (wr * 64 + mt * 16 + l15) * 64 +
                                          (((f * 4 + quad) ^ sw) * 8));
#pragma unroll
            for (int nt = 0; nt < 2; ++nt)
                bfr[nt] = *(const bf16x8*)(Bs + (wc * 32 + nt * 16 + l15) * 64 +
                                           (((f * 4 + quad) ^ sw) * 8));
#pragma unroll
            for (int mt = 0; mt < 4; ++mt)
#pragma unroll
                for (int nt = 0; nt < 2; ++nt)
                    acc[mt][nt] = MFMA16(af[mt], bfr[nt], acc[mt][nt]);
        }
        __syncthreads();
    }

    float bv[2];
#pragma unroll
    for (int nt = 0; nt < 2; ++nt) bv[nt] = bias[c0 + wc * 32 + nt * 16 + l15];
#pragma unroll
    for (int mt = 0; mt < 4; ++mt)
#pragma unroll
        for (int reg = 0; reg < 4; ++reg) {
            int gr = r0 + wr * 64 + mt * 16 + quad * 4 + reg;
#pragma unroll
            for (int nt = 0; nt < 2; ++nt) {
                int gc = c0 + wc * 32 + nt * 16 + l15;
                out[(size_t)gr * Dc + gc] = acc[mt][nt][reg] + bv[nt];
            }
        }
}

// ---------------------------------------------------------------------------
extern "C" void kernel_launch(void* const* d_in, const int* in_sizes, int n_in,
                              void* d_out, int out_size, void* d_ws, size_t ws_size,
                              hipStream_t stream) {
    const float* x      = (const float*)d_in[0];
    const float* W_qkv  = (const float*)d_in[1];
    const float* b_qkv  = (const float*)d_in[2];
    const float* W_proj = (const float*)d_in[3];
    const float* b_proj = (const float*)d_in[4];
    float* out = (float*)d_out;

    char* ws = (char*)d_ws;
    size_t off = 0;
    auto take = [&](size_t bytes) -> char* {
        char* p = ws + off;
        off += (bytes + 255) & ~(size_t)255;
        return p;
    };
    unsigned int*   cnt = (unsigned int*)take(256);
    unsigned short* WqT = (unsigned short*)take((size_t)Nqkv * Dc * 2);  // [2304][768]
    unsigned short* WpT = (unsigned short*)take((size_t)Dc * Dc * 2);    // [768][768]
    unsigned short* Qb  = (unsigned short*)take((size_t)BHc * Tc * DKc * 2);
    unsigned short* Kb  = (unsigned short*)take((size_t)BHc * Tc * DKc * 2);
    unsigned short* Vt  = (unsigned short*)take((size_t)BHc * Tc * DKc * 2);
    unsigned short* Xb  = (unsigned short*)take((size_t)Mc * Dc * 2);
    unsigned short* An  = Xb;  // alias: Xb dead after qkv_gemm

    hipMemsetAsync(cnt, 0, sizeof(unsigned int), stream);
    xconv_kernel<<<dim3((Mc * Dc) / (256 * 8)), dim3(256), 0, stream>>>(x, Xb);
    wtrans_kernel<<<dim3(Dc / 64, (Nqkv + Dc) / 64), dim3(256), 0, stream>>>(W_qkv, W_proj, WqT, WpT);
    qkv_gemm_kernel<<<dim3(Mc / 128, Nqkv / 128), dim3(256), 0, stream>>>(Xb, WqT, b_qkv, Qb, Kb, Vt);
    attn_kernel<<<dim3(NITEMS), dim3(256), 0, stream>>>(Qb, Kb, Vt, An, cnt);
    proj_gemm_kernel<<<dim3(Mc / 128, Dc / 64), dim3(256), 0, stream>>>(An, WpT, b_proj, out);
}